// Round 6
// baseline (202.881 us; speedup 1.0000x reference)
//
#include <hip/hip_runtime.h>

// Block-sparse attention, bf16x2 MFMA, deferred softmax, BARRIER-FREE K-loop.
// fp32 in/out. B=2 H=8 S=2048 D=64, BLOCK=64, nb=32.
// Pre-pass: K->(Khi,Klo) bf16 [bh][key][d]; V->Vtb bf16 [bh][kb][d][key].
// Main: one 64-thread WG (one wave) per (16-q-row tile, bh); grid 128x16=2048.
// B-frags are loaded straight from global (L1/L2-resident) -> no LDS staging,
// no __syncthreads in the loop. Only same-wave P LDS round-trip remains.

typedef __attribute__((ext_vector_type(8))) short short8;
typedef __attribute__((ext_vector_type(4))) short short4_;
typedef __attribute__((ext_vector_type(4))) float float4_;

#define B_   2
#define H_   8
#define S_   2048
#define D_   64
#define NB_  32
#define KP   72

__device__ __forceinline__ short f2bf(float f) {            // RNE float->bf16 bits
    union { float f; unsigned int u; } x; x.f = f;
    unsigned int r = x.u + 0x7FFFu + ((x.u >> 16) & 1u);
    return (short)(r >> 16);
}
__device__ __forceinline__ float bf2f(short s) {
    union { unsigned int u; float f; } x; x.u = ((unsigned int)(unsigned short)s) << 16;
    return x.f;
}

// ---------------- pre-pass: K -> hi/lo bf16, V -> per-block-transposed bf16 ----------------
__global__ __launch_bounds__(256)
void preconvert_kernel(const float* __restrict__ K, const float* __restrict__ V,
                       short* __restrict__ Khi, short* __restrict__ Klo,
                       short* __restrict__ Vtb) {
    __shared__ short vn[64 * KP];               // natural bf16 V tile [key][d]
    const int tid = threadIdx.x;
    const int kt  = blockIdx.x;                  // key tile 0..31
    const int bh  = blockIdx.y;                  // 0..15
    const size_t tb = ((size_t)bh * S_ + kt * 64) * D_;

#pragma unroll
    for (int it = 0; it < 4; ++it) {
        int i = tid + it * 256;
        int row = i >> 4, c4 = (i & 15) * 4;
        float4_ kv = *(const float4_*)(K + tb + row * D_ + c4);
        short4_ hi, lo;
#pragma unroll
        for (int e = 0; e < 4; ++e) {
            hi[e] = f2bf(kv[e]);
            lo[e] = f2bf(kv[e] - bf2f(hi[e]));
        }
        *(short4_*)(Khi + tb + row * D_ + c4) = hi;
        *(short4_*)(Klo + tb + row * D_ + c4) = lo;
        float4_ vv = *(const float4_*)(V + tb + row * D_ + c4);
        short4_ vb;
#pragma unroll
        for (int e = 0; e < 4; ++e) vb[e] = f2bf(vv[e]);
        *(short4_*)&vn[row * KP + c4] = vb;
    }
    __syncthreads();
    // block-transposed write: Vtb[bh][kt][d][key]
#pragma unroll
    for (int it = 0; it < 2; ++it) {
        int i = tid + it * 256;
        int rowd = i >> 3, key8 = (i & 7) * 8;
        short8 o;
#pragma unroll
        for (int e = 0; e < 8; ++e) o[e] = vn[(key8 + e) * KP + rowd];
        *(short8*)(Vtb + (((size_t)(bh * NB_ + kt)) * 64 + rowd) * 64 + key8) = o;
    }
}

// ---------------- main: barrier-free, one wave per 16 q rows ----------------
__global__ __launch_bounds__(64, 2)
void attn_mfma_nb(const float* __restrict__ Q,
                  const float* __restrict__ Msk,
                  const int* __restrict__ Mat,
                  float* __restrict__ O,
                  const short* __restrict__ Khi_g,
                  const short* __restrict__ Klo_g,
                  const short* __restrict__ Vtb_g) {
    __shared__ __align__(16) short Pl[16 * KP];   // per-wave P tile

    const int lane = threadIdx.x & 63;
    const int c    = lane & 15;
    const int quad = lane >> 4;

    const int qt = blockIdx.x;        // 16-row q tile 0..127
    const int bh = blockIdx.y;        // 0..15
    const int b  = bh / H_;
    const int qb = qt >> 2;           // 64-row block for Mat
    const size_t base = (size_t)bh * S_ * D_;

    // ---- Q A-frags, hi/lo split ----
    short8 qh0, qh1, ql0, ql1;
    {
        const float* qp = Q + base + (size_t)(qt * 16 + c) * D_ + quad * 8;
#pragma unroll
        for (int e = 0; e < 8; ++e) {
            float f0 = qp[e], f1 = qp[e + 32];
            qh0[e] = f2bf(f0); ql0[e] = f2bf(f0 - bf2f(qh0[e]));
            qh1[e] = f2bf(f1); ql1[e] = f2bf(f1 - bf2f(qh1[e]));
        }
    }

    float4_ o[4];
    float l_part[4];
#pragma unroll
    for (int t = 0; t < 4; ++t) { o[t][0] = 0.f; o[t][1] = 0.f; o[t][2] = 0.f; o[t][3] = 0.f; }
#pragma unroll
    for (int j = 0; j < 4; ++j) l_part[j] = 0.f;

    // ---- active-block bitmask (uniform across wave) ----
    unsigned long long bm = __ballot(Mat[qb * NB_ + (lane & 31)] != 0);
    unsigned int mbits = (unsigned int)(bm & 0xFFFFFFFFull);

    while (mbits) {
        const int kb = __builtin_ctz(mbits);
        mbits &= mbits - 1;

        const short* kh = Khi_g + base + (size_t)kb * 64 * D_;
        const short* kl = Klo_g + base + (size_t)kb * 64 * D_;
        const short* vt = Vtb_g + ((size_t)(bh * NB_ + kb)) * 64 * 64;

        // ---- issue all fragment loads (independent; compiler overlaps) ----
        short8 KH0[4], KH1[4], KL0[4], KL1[4], VB0[4], VB1[4];
        float biasv[4];
#pragma unroll
        for (int t = 0; t < 4; ++t) {
            const int off = (t * 16 + c) * 64 + quad * 8;
            VB0[t] = *(const short8*)(vt + off);
            VB1[t] = *(const short8*)(vt + off + 32);
            KH0[t] = *(const short8*)(kh + off);
            KH1[t] = *(const short8*)(kh + off + 32);
            KL0[t] = *(const short8*)(kl + off);
            KL1[t] = *(const short8*)(kl + off + 32);
            biasv[t] = -1.0e6f * (1.0f - Msk[(size_t)b * S_ + kb * 64 + t * 16 + c]);
        }

        // ---- scores: hi*hi + hi*lo + lo*hi, 2 k-steps, 4 n-tiles ----
        float4_ sc[4];
#pragma unroll
        for (int t = 0; t < 4; ++t) { sc[t][0] = 0.f; sc[t][1] = 0.f; sc[t][2] = 0.f; sc[t][3] = 0.f; }
#pragma unroll
        for (int t = 0; t < 4; ++t) {
            sc[t] = __builtin_amdgcn_mfma_f32_16x16x32_bf16(qh0, KH0[t], sc[t], 0, 0, 0);
            sc[t] = __builtin_amdgcn_mfma_f32_16x16x32_bf16(qh1, KH1[t], sc[t], 0, 0, 0);
            sc[t] = __builtin_amdgcn_mfma_f32_16x16x32_bf16(qh0, KL0[t], sc[t], 0, 0, 0);
            sc[t] = __builtin_amdgcn_mfma_f32_16x16x32_bf16(qh1, KL1[t], sc[t], 0, 0, 0);
            sc[t] = __builtin_amdgcn_mfma_f32_16x16x32_bf16(ql0, KH0[t], sc[t], 0, 0, 0);
            sc[t] = __builtin_amdgcn_mfma_f32_16x16x32_bf16(ql1, KH1[t], sc[t], 0, 0, 0);
        }

        // ---- P = exp(s + bias); per-lane l partial; P -> LDS (same wave) ----
#pragma unroll
        for (int t = 0; t < 4; ++t) {
#pragma unroll
            for (int j = 0; j < 4; ++j) {
                float p = __expf(sc[t][j] + biasv[t]);
                l_part[j] += p;
                Pl[(quad * 4 + j) * KP + t * 16 + c] = f2bf(p);
            }
        }

        // ---- P A-frags (same-wave DS ordering) ----
        const short* pp = Pl + c * KP + quad * 8;
        short8 pa0 = *(const short8*)(pp);
        short8 pa1 = *(const short8*)(pp + 32);

        // ---- O += P * V ----
#pragma unroll
        for (int t = 0; t < 4; ++t) {
            o[t] = __builtin_amdgcn_mfma_f32_16x16x32_bf16(pa0, VB0[t], o[t], 0, 0, 0);
            o[t] = __builtin_amdgcn_mfma_f32_16x16x32_bf16(pa1, VB1[t], o[t], 0, 0, 0);
        }
    }

    // ---- epilogue: reduce l across the 16 column-lanes once, normalize, store ----
#pragma unroll
    for (int j = 0; j < 4; ++j) {
        float rs = l_part[j];
        rs += __shfl_xor(rs, 1);
        rs += __shfl_xor(rs, 2);
        rs += __shfl_xor(rs, 4);
        rs += __shfl_xor(rs, 8);
        float inv = 1.0f / rs;
        size_t rowoff = base + (size_t)(qt * 16 + quad * 4 + j) * D_;
#pragma unroll
        for (int t = 0; t < 4; ++t)
            O[rowoff + t * 16 + c] = o[t][j] * inv;
    }
}

// ---------------- fallback (no workspace): round-5 LDS-staging kernel ----------------
__global__ __launch_bounds__(256, 2)
void attn_mfma_fb(const float* __restrict__ Q,
                  const float* __restrict__ K,
                  const float* __restrict__ V,
                  const float* __restrict__ Msk,
                  const int* __restrict__ Mat,
                  float* __restrict__ O) {
    __shared__ __align__(16) short lds[4 * 64 * KP];
    short* Khi = lds;
    short* Klo = lds + 64 * KP;
    short* Vt  = lds + 2 * 64 * KP;
    short* Pl  = lds + 3 * 64 * KP;

    const int tid  = threadIdx.x;
    const int wave = tid >> 6;
    const int lane = tid & 63;
    const int c    = lane & 15;
    const int quad = lane >> 4;

    const int qb = blockIdx.x;
    const int bh = blockIdx.y;
    const int b  = bh / H_;
    const size_t base = (size_t)bh * S_ * D_;

    short8 qh0, qh1, ql0, ql1;
    {
        const float* qp = Q + base + (size_t)(qb * 64 + wave * 16 + c) * D_ + quad * 8;
#pragma unroll
        for (int e = 0; e < 8; ++e) {
            float f0 = qp[e], f1 = qp[e + 32];
            qh0[e] = f2bf(f0); ql0[e] = f2bf(f0 - bf2f(qh0[e]));
            qh1[e] = f2bf(f1); ql1[e] = f2bf(f1 - bf2f(qh1[e]));
        }
    }

    float4_ o[4];
    float l_part[4];
#pragma unroll
    for (int t = 0; t < 4; ++t) { o[t][0] = 0.f; o[t][1] = 0.f; o[t][2] = 0.f; o[t][3] = 0.f; }
#pragma unroll
    for (int j = 0; j < 4; ++j) l_part[j] = 0.f;

    for (int kb = 0; kb < NB_; ++kb) {
        if (Mat[qb * NB_ + kb] == 0) continue;

        __syncthreads();
        {
            const float* kg = K + base + (size_t)kb * 64 * D_;
            const float* vg = V + base + (size_t)kb * 64 * D_;
#pragma unroll
            for (int it = 0; it < 4; ++it) {
                int i = tid + it * 256;
                int row = i >> 4, c4 = (i & 15) * 4;
                float4_ kv = *(const float4_*)(kg + row * D_ + c4);
                short4_ hi, lo;
#pragma unroll
                for (int e = 0; e < 4; ++e) {
                    hi[e] = f2bf(kv[e]);
                    lo[e] = f2bf(kv[e] - bf2f(hi[e]));
                }
                *(short4_*)&Khi[row * KP + c4] = hi;
                *(short4_*)&Klo[row * KP + c4] = lo;
                float4_ vv = *(const float4_*)(vg + row * D_ + c4);
#pragma unroll
                for (int e = 0; e < 4; ++e) Vt[(c4 + e) * KP + row] = f2bf(vv[e]);
            }
        }
        __syncthreads();

        float4_ sc[4];
#pragma unroll
        for (int t = 0; t < 4; ++t) { sc[t][0] = 0.f; sc[t][1] = 0.f; sc[t][2] = 0.f; sc[t][3] = 0.f; }
#pragma unroll
        for (int t = 0; t < 4; ++t) {
            const short* kph = &Khi[(t * 16 + c) * KP + quad * 8];
            const short* kpl = &Klo[(t * 16 + c) * KP + quad * 8];
            short8 kh0 = *(const short8*)(kph);
            short8 kh1 = *(const short8*)(kph + 32);
            short8 kl0 = *(const short8*)(kpl);
            short8 kl1 = *(const short8*)(kpl + 32);
            sc[t] = __builtin_amdgcn_mfma_f32_16x16x32_bf16(qh0, kh0, sc[t], 0, 0, 0);
            sc[t] = __builtin_amdgcn_mfma_f32_16x16x32_bf16(qh1, kh1, sc[t], 0, 0, 0);
            sc[t] = __builtin_amdgcn_mfma_f32_16x16x32_bf16(qh0, kl0, sc[t], 0, 0, 0);
            sc[t] = __builtin_amdgcn_mfma_f32_16x16x32_bf16(qh1, kl1, sc[t], 0, 0, 0);
            sc[t] = __builtin_amdgcn_mfma_f32_16x16x32_bf16(ql0, kh0, sc[t], 0, 0, 0);
            sc[t] = __builtin_amdgcn_mfma_f32_16x16x32_bf16(ql1, kh1, sc[t], 0, 0, 0);
        }

        short* Pw = Pl + wave * 16 * KP;
#pragma unroll
        for (int t = 0; t < 4; ++t) {
            float bias = -1.0e6f * (1.0f - Msk[(size_t)b * S_ + kb * 64 + t * 16 + c]);
#pragma unroll
            for (int j = 0; j < 4; ++j) {
                float p = __expf(sc[t][j] + bias);
                l_part[j] += p;
                Pw[(quad * 4 + j) * KP + t * 16 + c] = f2bf(p);
            }
        }

        const short* pp = Pl + wave * 16 * KP + c * KP + quad * 8;
        short8 pa0 = *(const short8*)(pp);
        short8 pa1 = *(const short8*)(pp + 32);

#pragma unroll
        for (int t = 0; t < 4; ++t) {
            const short* vp = &Vt[(t * 16 + c) * KP + quad * 8];
            short8 vb0 = *(const short8*)(vp);
            short8 vb1 = *(const short8*)(vp + 32);
            o[t] = __builtin_amdgcn_mfma_f32_16x16x32_bf16(pa0, vb0, o[t], 0, 0, 0);
            o[t] = __builtin_amdgcn_mfma_f32_16x16x32_bf16(pa1, vb1, o[t], 0, 0, 0);
        }
    }

#pragma unroll
    for (int j = 0; j < 4; ++j) {
        float rs = l_part[j];
        rs += __shfl_xor(rs, 1);
        rs += __shfl_xor(rs, 2);
        rs += __shfl_xor(rs, 4);
        rs += __shfl_xor(rs, 8);
        float inv = 1.0f / rs;
        size_t rowoff = base + (size_t)(qb * 64 + wave * 16 + quad * 4 + j) * D_;
#pragma unroll
        for (int t = 0; t < 4; ++t)
            O[rowoff + t * 16 + c] = o[t][j] * inv;
    }
}

extern "C" void kernel_launch(void* const* d_in, const int* in_sizes, int n_in,
                              void* d_out, int out_size, void* d_ws, size_t ws_size,
                              hipStream_t stream) {
    const float* q   = (const float*)d_in[0];
    const float* k   = (const float*)d_in[1];
    const float* v   = (const float*)d_in[2];
    const float* msk = (const float*)d_in[3];
    const int*   mat = (const int*)d_in[4];
    float*       out = (float*)d_out;

    const size_t elems = (size_t)B_ * H_ * S_ * D_;      // 2.1M
    const size_t need  = 3 * elems * sizeof(short);      // 12.6 MB
    const int use_pre  = (ws_size >= need) ? 1 : 0;      // deterministic per-call

    short* khi = (short*)d_ws;
    short* klo = khi + elems;
    short* vtb = klo + elems;

    if (use_pre) {
        dim3 pgrid(NB_, B_ * H_);
        preconvert_kernel<<<pgrid, dim3(256), 0, stream>>>(k, v, khi, klo, vtb);
        dim3 grid(S_ / 16, B_ * H_);                     // 128 x 16 single-wave WGs
        attn_mfma_nb<<<grid, dim3(64), 0, stream>>>(q, msk, mat, out, khi, klo, vtb);
    } else {
        dim3 grid(NB_, B_ * H_);
        attn_mfma_fb<<<grid, dim3(256), 0, stream>>>(q, k, v, msk, mat, out);
    }
}

// Round 7
// 119.372 us; speedup vs baseline: 1.6996x; 1.6996x over previous
//
#include <hip/hip_runtime.h>

// Block-sparse attention, bf16x2 MFMA, deferred softmax, software-pipelined
// LDS staging. fp32 in/out. B=2 H=8 S=2048 D=64, BLOCK=64, nb=32.
// Round-6 lesson: per-wave global fragment loads destroyed 4-wave reuse (4x
// VMEM traffic, FETCH 54->117MB). Revert to shared LDS staging; hide the
// staging latency by prefetching block kb+1 into VGPRs during compute on kb.
// Pre-pass: K->(Khi,Klo) bf16 [bh][key][d]; V->Vtb bf16 [bh][kb][d][key].

typedef __attribute__((ext_vector_type(8))) short short8;
typedef __attribute__((ext_vector_type(4))) short short4_;
typedef __attribute__((ext_vector_type(4))) float float4_;

#define B_   2
#define H_   8
#define S_   2048
#define D_   64
#define NB_  32
#define KP   72   // padded LDS row stride (shorts)

__device__ __forceinline__ short f2bf(float f) {            // RNE float->bf16 bits
    union { float f; unsigned int u; } x; x.f = f;
    unsigned int r = x.u + 0x7FFFu + ((x.u >> 16) & 1u);
    return (short)(r >> 16);
}
__device__ __forceinline__ float bf2f(short s) {
    union { unsigned int u; float f; } x; x.u = ((unsigned int)(unsigned short)s) << 16;
    return x.f;
}

// ---------------- pre-pass: K -> hi/lo bf16, V -> per-block-transposed bf16 ----------------
__global__ __launch_bounds__(256)
void preconvert_kernel(const float* __restrict__ K, const float* __restrict__ V,
                       short* __restrict__ Khi, short* __restrict__ Klo,
                       short* __restrict__ Vtb) {
    __shared__ short vn[64 * KP];               // natural bf16 V tile [key][d]
    const int tid = threadIdx.x;
    const int kt  = blockIdx.x;                  // key tile 0..31
    const int bh  = blockIdx.y;                  // 0..15
    const size_t tb = ((size_t)bh * S_ + kt * 64) * D_;

#pragma unroll
    for (int it = 0; it < 4; ++it) {
        int i = tid + it * 256;
        int row = i >> 4, c4 = (i & 15) * 4;
        float4_ kv = *(const float4_*)(K + tb + row * D_ + c4);
        short4_ hi, lo;
#pragma unroll
        for (int e = 0; e < 4; ++e) {
            hi[e] = f2bf(kv[e]);
            lo[e] = f2bf(kv[e] - bf2f(hi[e]));
        }
        *(short4_*)(Khi + tb + row * D_ + c4) = hi;
        *(short4_*)(Klo + tb + row * D_ + c4) = lo;
        float4_ vv = *(const float4_*)(V + tb + row * D_ + c4);
        short4_ vb;
#pragma unroll
        for (int e = 0; e < 4; ++e) vb[e] = f2bf(vv[e]);
        *(short4_*)&vn[row * KP + c4] = vb;
    }
    __syncthreads();
    // block-transposed write: Vtb[bh][kt][d][key]  (contiguous 8KB per block)
#pragma unroll
    for (int it = 0; it < 2; ++it) {
        int i = tid + it * 256;
        int rowd = i >> 3, key8 = (i & 7) * 8;
        short8 o;
#pragma unroll
        for (int e = 0; e < 8; ++e) o[e] = vn[(key8 + e) * KP + rowd];
        *(short8*)(Vtb + (((size_t)(bh * NB_ + kt)) * 64 + rowd) * 64 + key8) = o;
    }
}

// ---------------- main: LDS staging + VGPR prefetch pipeline ----------------
__global__ __launch_bounds__(256, 2)
void attn_mfma_pl(const float* __restrict__ Q,
                  const float* __restrict__ Msk,
                  const int* __restrict__ Mat,
                  float* __restrict__ O,
                  const short* __restrict__ Khi_g,
                  const short* __restrict__ Klo_g,
                  const short* __restrict__ Vtb_g) {
    __shared__ __align__(16) short lds[4 * 64 * KP];   // Khi | Klo | Vt | P(4 waves)
    short* Khi = lds;
    short* Klo = lds + 64 * KP;
    short* Vt  = lds + 2 * 64 * KP;
    short* Pl  = lds + 3 * 64 * KP;

    const int tid  = threadIdx.x;
    const int wave = tid >> 6;
    const int lane = tid & 63;
    const int c    = lane & 15;
    const int quad = lane >> 4;

    const int qb = blockIdx.x;
    const int bh = blockIdx.y;
    const int b  = bh / H_;
    const size_t base = (size_t)bh * S_ * D_;

    // staging chunk coords for this thread (2 chunks of 8 shorts per array)
    const int row0 = tid >> 3,          col0 = (tid & 7) * 8;
    const int row1 = (tid + 256) >> 3,  col1 = (tid & 7) * 8;   // rows 32..63

    // ---- Q A-frags, hi/lo split ----
    short8 qh0, qh1, ql0, ql1;
    {
        const float* qp = Q + base + (size_t)(qb * 64 + wave * 16 + c) * D_ + quad * 8;
#pragma unroll
        for (int e = 0; e < 8; ++e) {
            float f0 = qp[e], f1 = qp[e + 32];
            qh0[e] = f2bf(f0); ql0[e] = f2bf(f0 - bf2f(qh0[e]));
            qh1[e] = f2bf(f1); ql1[e] = f2bf(f1 - bf2f(qh1[e]));
        }
    }

    float4_ o[4];
    float l_part[4];
#pragma unroll
    for (int t = 0; t < 4; ++t) { o[t][0] = 0.f; o[t][1] = 0.f; o[t][2] = 0.f; o[t][3] = 0.f; }
#pragma unroll
    for (int j = 0; j < 4; ++j) l_part[j] = 0.f;

    // ---- active-block bitmask (uniform across WG) ----
    unsigned long long bm = __ballot(Mat[qb * NB_ + (lane & 31)] != 0);
    unsigned int mbits = (unsigned int)(bm & 0xFFFFFFFFull);

    // prefetch registers
    short8 sK0, sK1, sL0, sL1, sV0, sV1;
    float  biasn[4];

    // ---- prologue: prefetch first active block ----
    int kb = __builtin_ctz(mbits);
    mbits &= mbits - 1;
    {
        const short* kh = Khi_g + base + (size_t)kb * 64 * D_;
        const short* kl = Klo_g + base + (size_t)kb * 64 * D_;
        const short* vt = Vtb_g + ((size_t)(bh * NB_ + kb)) * 64 * 64;
        sK0 = *(const short8*)(kh + row0 * 64 + col0);
        sK1 = *(const short8*)(kh + row1 * 64 + col1);
        sL0 = *(const short8*)(kl + row0 * 64 + col0);
        sL1 = *(const short8*)(kl + row1 * 64 + col1);
        sV0 = *(const short8*)(vt + row0 * 64 + col0);
        sV1 = *(const short8*)(vt + row1 * 64 + col1);
#pragma unroll
        for (int t = 0; t < 4; ++t)
            biasn[t] = -1.0e6f * (1.0f - Msk[(size_t)b * S_ + kb * 64 + t * 16 + c]);
    }

    for (;;) {
        __syncthreads();   // all waves done reading LDS from previous iteration
        // ---- commit prefetched block to LDS ----
        *(short8*)&Khi[row0 * KP + col0] = sK0;
        *(short8*)&Khi[row1 * KP + col1] = sK1;
        *(short8*)&Klo[row0 * KP + col0] = sL0;
        *(short8*)&Klo[row1 * KP + col1] = sL1;
        *(short8*)&Vt[row0 * KP + col0]  = sV0;
        *(short8*)&Vt[row1 * KP + col1]  = sV1;
        float biasc[4];
#pragma unroll
        for (int t = 0; t < 4; ++t) biasc[t] = biasn[t];
        __syncthreads();

        // ---- issue prefetch for the NEXT active block (overlaps compute below) ----
        const bool have_next = (mbits != 0);
        if (have_next) {
            kb = __builtin_ctz(mbits);
            mbits &= mbits - 1;
            const short* kh = Khi_g + base + (size_t)kb * 64 * D_;
            const short* kl = Klo_g + base + (size_t)kb * 64 * D_;
            const short* vt = Vtb_g + ((size_t)(bh * NB_ + kb)) * 64 * 64;
            sK0 = *(const short8*)(kh + row0 * 64 + col0);
            sK1 = *(const short8*)(kh + row1 * 64 + col1);
            sL0 = *(const short8*)(kl + row0 * 64 + col0);
            sL1 = *(const short8*)(kl + row1 * 64 + col1);
            sV0 = *(const short8*)(vt + row0 * 64 + col0);
            sV1 = *(const short8*)(vt + row1 * 64 + col1);
#pragma unroll
            for (int t = 0; t < 4; ++t)
                biasn[t] = -1.0e6f * (1.0f - Msk[(size_t)b * S_ + kb * 64 + t * 16 + c]);
        }

        // ---- scores: hi*hi + hi*lo + lo*hi, 2 k-steps, 4 n-tiles ----
        float4_ sc[4];
#pragma unroll
        for (int t = 0; t < 4; ++t) { sc[t][0] = 0.f; sc[t][1] = 0.f; sc[t][2] = 0.f; sc[t][3] = 0.f; }
#pragma unroll
        for (int t = 0; t < 4; ++t) {
            const short* kph = &Khi[(t * 16 + c) * KP + quad * 8];
            const short* kpl = &Klo[(t * 16 + c) * KP + quad * 8];
            short8 kh0 = *(const short8*)(kph);
            short8 kh1 = *(const short8*)(kph + 32);
            short8 kl0 = *(const short8*)(kpl);
            short8 kl1 = *(const short8*)(kpl + 32);
            sc[t] = __builtin_amdgcn_mfma_f32_16x16x32_bf16(qh0, kh0, sc[t], 0, 0, 0);
            sc[t] = __builtin_amdgcn_mfma_f32_16x16x32_bf16(qh1, kh1, sc[t], 0, 0, 0);
            sc[t] = __builtin_amdgcn_mfma_f32_16x16x32_bf16(qh0, kl0, sc[t], 0, 0, 0);
            sc[t] = __builtin_amdgcn_mfma_f32_16x16x32_bf16(qh1, kl1, sc[t], 0, 0, 0);
            sc[t] = __builtin_amdgcn_mfma_f32_16x16x32_bf16(ql0, kh0, sc[t], 0, 0, 0);
            sc[t] = __builtin_amdgcn_mfma_f32_16x16x32_bf16(ql1, kh1, sc[t], 0, 0, 0);
        }

        // ---- P = exp(s + bias); per-lane l partial; P -> per-wave LDS ----
        short* Pw = Pl + wave * 16 * KP;
#pragma unroll
        for (int t = 0; t < 4; ++t) {
#pragma unroll
            for (int j = 0; j < 4; ++j) {
                float p = __expf(sc[t][j] + biasc[t]);
                l_part[j] += p;
                Pw[(quad * 4 + j) * KP + t * 16 + c] = f2bf(p);
            }
        }

        // ---- P A-frags (same-wave DS ordering) ----
        const short* pp = Pl + wave * 16 * KP + c * KP + quad * 8;
        short8 pa0 = *(const short8*)(pp);
        short8 pa1 = *(const short8*)(pp + 32);

        // ---- O += P * V ----
#pragma unroll
        for (int t = 0; t < 4; ++t) {
            const short* vp = &Vt[(t * 16 + c) * KP + quad * 8];
            short8 vb0 = *(const short8*)(vp);
            short8 vb1 = *(const short8*)(vp + 32);
            o[t] = __builtin_amdgcn_mfma_f32_16x16x32_bf16(pa0, vb0, o[t], 0, 0, 0);
            o[t] = __builtin_amdgcn_mfma_f32_16x16x32_bf16(pa1, vb1, o[t], 0, 0, 0);
        }

        if (!have_next) break;
    }

    // ---- epilogue: reduce l across the 16 column-lanes once, normalize, store ----
#pragma unroll
    for (int j = 0; j < 4; ++j) {
        float rs = l_part[j];
        rs += __shfl_xor(rs, 1);
        rs += __shfl_xor(rs, 2);
        rs += __shfl_xor(rs, 4);
        rs += __shfl_xor(rs, 8);
        float inv = 1.0f / rs;
        size_t rowoff = base + (size_t)(qb * 64 + wave * 16 + quad * 4 + j) * D_;
#pragma unroll
        for (int t = 0; t < 4; ++t)
            O[rowoff + t * 16 + c] = o[t][j] * inv;
    }
}

// ---------------- fallback (no workspace): round-5 LDS-staging kernel ----------------
__global__ __launch_bounds__(256, 2)
void attn_mfma_fb(const float* __restrict__ Q,
                  const float* __restrict__ K,
                  const float* __restrict__ V,
                  const float* __restrict__ Msk,
                  const int* __restrict__ Mat,
                  float* __restrict__ O) {
    __shared__ __align__(16) short lds[4 * 64 * KP];
    short* Khi = lds;
    short* Klo = lds + 64 * KP;
    short* Vt  = lds + 2 * 64 * KP;
    short* Pl  = lds + 3 * 64 * KP;

    const int tid  = threadIdx.x;
    const int wave = tid >> 6;
    const int lane = tid & 63;
    const int c    = lane & 15;
    const int quad = lane >> 4;

    const int qb = blockIdx.x;
    const int bh = blockIdx.y;
    const int b  = bh / H_;
    const size_t base = (size_t)bh * S_ * D_;

    short8 qh0, qh1, ql0, ql1;
    {
        const float* qp = Q + base + (size_t)(qb * 64 + wave * 16 + c) * D_ + quad * 8;
#pragma unroll
        for (int e = 0; e < 8; ++e) {
            float f0 = qp[e], f1 = qp[e + 32];
            qh0[e] = f2bf(f0); ql0[e] = f2bf(f0 - bf2f(qh0[e]));
            qh1[e] = f2bf(f1); ql1[e] = f2bf(f1 - bf2f(qh1[e]));
        }
    }

    float4_ o[4];
    float l_part[4];
#pragma unroll
    for (int t = 0; t < 4; ++t) { o[t][0] = 0.f; o[t][1] = 0.f; o[t][2] = 0.f; o[t][3] = 0.f; }
#pragma unroll
    for (int j = 0; j < 4; ++j) l_part[j] = 0.f;

    for (int kb = 0; kb < NB_; ++kb) {
        if (Mat[qb * NB_ + kb] == 0) continue;

        __syncthreads();
        {
            const float* kg = K + base + (size_t)kb * 64 * D_;
            const float* vg = V + base + (size_t)kb * 64 * D_;
#pragma unroll
            for (int it = 0; it < 4; ++it) {
                int i = tid + it * 256;
                int row = i >> 4, c4 = (i & 15) * 4;
                float4_ kv = *(const float4_*)(kg + row * D_ + c4);
                short4_ hi, lo;
#pragma unroll
                for (int e = 0; e < 4; ++e) {
                    hi[e] = f2bf(kv[e]);
                    lo[e] = f2bf(kv[e] - bf2f(hi[e]));
                }
                *(short4_*)&Khi[row * KP + c4] = hi;
                *(short4_*)&Klo[row * KP + c4] = lo;
                float4_ vv = *(const float4_*)(vg + row * D_ + c4);
#pragma unroll
                for (int e = 0; e < 4; ++e) Vt[(c4 + e) * KP + row] = f2bf(vv[e]);
            }
        }
        __syncthreads();

        float4_ sc[4];
#pragma unroll
        for (int t = 0; t < 4; ++t) { sc[t][0] = 0.f; sc[t][1] = 0.f; sc[t][2] = 0.f; sc[t][3] = 0.f; }
#pragma unroll
        for (int t = 0; t < 4; ++t) {
            const short* kph = &Khi[(t * 16 + c) * KP + quad * 8];
            const short* kpl = &Klo[(t * 16 + c) * KP + quad * 8];
            short8 kh0 = *(const short8*)(kph);
            short8 kh1 = *(const short8*)(kph + 32);
            short8 kl0 = *(const short8*)(kpl);
            short8 kl1 = *(const short8*)(kpl + 32);
            sc[t] = __builtin_amdgcn_mfma_f32_16x16x32_bf16(qh0, kh0, sc[t], 0, 0, 0);
            sc[t] = __builtin_amdgcn_mfma_f32_16x16x32_bf16(qh1, kh1, sc[t], 0, 0, 0);
            sc[t] = __builtin_amdgcn_mfma_f32_16x16x32_bf16(qh0, kl0, sc[t], 0, 0, 0);
            sc[t] = __builtin_amdgcn_mfma_f32_16x16x32_bf16(qh1, kl1, sc[t], 0, 0, 0);
            sc[t] = __builtin_amdgcn_mfma_f32_16x16x32_bf16(ql0, kh0, sc[t], 0, 0, 0);
            sc[t] = __builtin_amdgcn_mfma_f32_16x16x32_bf16(ql1, kh1, sc[t], 0, 0, 0);
        }

        short* Pw = Pl + wave * 16 * KP;
#pragma unroll
        for (int t = 0; t < 4; ++t) {
            float bias = -1.0e6f * (1.0f - Msk[(size_t)b * S_ + kb * 64 + t * 16 + c]);
#pragma unroll
            for (int j = 0; j < 4; ++j) {
                float p = __expf(sc[t][j] + bias);
                l_part[j] += p;
                Pw[(quad * 4 + j) * KP + t * 16 + c] = f2bf(p);
            }
        }

        const short* pp = Pl + wave * 16 * KP + c * KP + quad * 8;
        short8 pa0 = *(const short8*)(pp);
        short8 pa1 = *(const short8*)(pp + 32);

#pragma unroll
        for (int t = 0; t < 4; ++t) {
            const short* vp = &Vt[(t * 16 + c) * KP + quad * 8];
            short8 vb0 = *(const short8*)(vp);
            short8 vb1 = *(const short8*)(vp + 32);
            o[t] = __builtin_amdgcn_mfma_f32_16x16x32_bf16(pa0, vb0, o[t], 0, 0, 0);
            o[t] = __builtin_amdgcn_mfma_f32_16x16x32_bf16(pa1, vb1, o[t], 0, 0, 0);
        }
    }

#pragma unroll
    for (int j = 0; j < 4; ++j) {
        float rs = l_part[j];
        rs += __shfl_xor(rs, 1);
        rs += __shfl_xor(rs, 2);
        rs += __shfl_xor(rs, 4);
        rs += __shfl_xor(rs, 8);
        float inv = 1.0f / rs;
        size_t rowoff = base + (size_t)(qb * 64 + wave * 16 + quad * 4 + j) * D_;
#pragma unroll
        for (int t = 0; t < 4; ++t)
            O[rowoff + t * 16 + c] = o[t][j] * inv;
    }
}

extern "C" void kernel_launch(void* const* d_in, const int* in_sizes, int n_in,
                              void* d_out, int out_size, void* d_ws, size_t ws_size,
                              hipStream_t stream) {
    const float* q   = (const float*)d_in[0];
    const float* k   = (const float*)d_in[1];
    const float* v   = (const float*)d_in[2];
    const float* msk = (const float*)d_in[3];
    const int*   mat = (const int*)d_in[4];
    float*       out = (float*)d_out;

    const size_t elems = (size_t)B_ * H_ * S_ * D_;      // 2.1M
    const size_t need  = 3 * elems * sizeof(short);      // 12.6 MB
    const int use_pre  = (ws_size >= need) ? 1 : 0;      // deterministic per-call

    short* khi = (short*)d_ws;
    short* klo = khi + elems;
    short* vtb = klo + elems;

    dim3 grid(NB_, B_ * H_);
    if (use_pre) {
        preconvert_kernel<<<grid, dim3(256), 0, stream>>>(k, v, khi, klo, vtb);
        attn_mfma_pl<<<grid, dim3(256), 0, stream>>>(q, msk, mat, out, khi, klo, vtb);
    } else {
        attn_mfma_fb<<<grid, dim3(256), 0, stream>>>(q, k, v, msk, mat, out);
    }
}

// Round 8
// 112.921 us; speedup vs baseline: 1.7967x; 1.0571x over previous
//
#include <hip/hip_runtime.h>

// Block-sparse attention, fp16 QK + bf16 PV MFMA, deferred softmax,
// software-pipelined LDS staging, 128-thr WGs (32 q rows, 2 waves).
// fp32 in/out. B=2 H=8 S=2048 D=64, BLOCK=64, nb=32.
// R6 lesson: keep LDS staging (reuse). R7 lesson: latency-bound -> cut the
// per-iter chain (fp16 single-pass QK, -40% work) and split WGs (4 independent
// barrier domains per CU instead of 2).
// Pre-pass: K -> fp16 [bh][key][d]; V -> bf16 Vtb [bh][kb][d][key].

typedef __attribute__((ext_vector_type(8))) short short8;
typedef __attribute__((ext_vector_type(4))) short short4_;
typedef __attribute__((ext_vector_type(4))) float float4_;
typedef __attribute__((ext_vector_type(8))) _Float16 half8_;

#define B_   2
#define H_   8
#define S_   2048
#define D_   64
#define NB_  32
#define KP   72   // padded LDS row stride (shorts)

__device__ __forceinline__ short f2bf(float f) {            // RNE float->bf16 bits
    union { float f; unsigned int u; } x; x.f = f;
    unsigned int r = x.u + 0x7FFFu + ((x.u >> 16) & 1u);
    return (short)(r >> 16);
}
__device__ __forceinline__ float bf2f(short s) {
    union { unsigned int u; float f; } x; x.u = ((unsigned int)(unsigned short)s) << 16;
    return x.f;
}
__device__ __forceinline__ short f2h(float f) {             // fp32 -> fp16 bits
    _Float16 h = (_Float16)f;
    return __builtin_bit_cast(short, h);
}

// ---------------- pre-pass: K -> fp16, V -> per-block-transposed bf16 ----------------
__global__ __launch_bounds__(256)
void preconvert_kernel(const float* __restrict__ K, const float* __restrict__ V,
                       short* __restrict__ Khf, short* __restrict__ Vtb) {
    __shared__ short vn[64 * KP];               // natural bf16 V tile [key][d]
    const int tid = threadIdx.x;
    const int kt  = blockIdx.x;                  // key tile 0..31
    const int bh  = blockIdx.y;                  // 0..15
    const size_t tb = ((size_t)bh * S_ + kt * 64) * D_;

#pragma unroll
    for (int it = 0; it < 4; ++it) {
        int i = tid + it * 256;
        int row = i >> 4, c4 = (i & 15) * 4;
        float4_ kv = *(const float4_*)(K + tb + row * D_ + c4);
        short4_ kh;
#pragma unroll
        for (int e = 0; e < 4; ++e) kh[e] = f2h(kv[e]);
        *(short4_*)(Khf + tb + row * D_ + c4) = kh;
        float4_ vv = *(const float4_*)(V + tb + row * D_ + c4);
        short4_ vb;
#pragma unroll
        for (int e = 0; e < 4; ++e) vb[e] = f2bf(vv[e]);
        *(short4_*)&vn[row * KP + c4] = vb;
    }
    __syncthreads();
    // block-transposed write: Vtb[bh][kt][d][key]  (contiguous 8KB per block)
#pragma unroll
    for (int it = 0; it < 2; ++it) {
        int i = tid + it * 256;
        int rowd = i >> 3, key8 = (i & 7) * 8;
        short8 o;
#pragma unroll
        for (int e = 0; e < 8; ++e) o[e] = vn[(key8 + e) * KP + rowd];
        *(short8*)(Vtb + (((size_t)(bh * NB_ + kt)) * 64 + rowd) * 64 + key8) = o;
    }
}

// ---------------- main: 128-thr WG, 32 q rows, fp16 QK, prefetch pipeline ----------------
__global__ __launch_bounds__(128, 2)
void attn_mfma_h(const float* __restrict__ Q,
                 const float* __restrict__ Msk,
                 const int* __restrict__ Mat,
                 float* __restrict__ O,
                 const short* __restrict__ Khf_g,
                 const short* __restrict__ Vtb_g) {
    __shared__ __align__(16) short lds[(64 + 64 + 2 * 16) * KP];   // Kh | Vt | P(2 waves)
    short* Kh = lds;
    short* Vt = lds + 64 * KP;
    short* Pl = lds + 2 * 64 * KP;

    const int tid  = threadIdx.x;
    const int wave = tid >> 6;
    const int lane = tid & 63;
    const int c    = lane & 15;
    const int quad = lane >> 4;

    const int qt = blockIdx.x;        // 32-row q tile 0..63
    const int bh = blockIdx.y;        // 0..15
    const int b  = bh / H_;
    const int qb = qt >> 1;           // 64-row block for Mat
    const size_t base = (size_t)bh * S_ * D_;

    // ---- Q A-frags in fp16 (A[m=lane&15][k=quad*8+j], two 32-wide k-steps) ----
    half8_ qa0, qa1;
    {
        const float* qp = Q + base + (size_t)(qt * 32 + wave * 16 + c) * D_ + quad * 8;
#pragma unroll
        for (int e = 0; e < 8; ++e) {
            qa0[e] = (_Float16)qp[e];
            qa1[e] = (_Float16)qp[e + 32];
        }
    }

    float4_ o[4];
    float l_part[4];
#pragma unroll
    for (int t = 0; t < 4; ++t) { o[t][0] = 0.f; o[t][1] = 0.f; o[t][2] = 0.f; o[t][3] = 0.f; }
#pragma unroll
    for (int j = 0; j < 4; ++j) l_part[j] = 0.f;

    // ---- active-block bitmask (uniform across WG) ----
    unsigned long long bm = __ballot(Mat[qb * NB_ + (lane & 31)] != 0);
    unsigned int mbits = (unsigned int)(bm & 0xFFFFFFFFull);

    // staging chunk coords: 4 chunks of 8 shorts per array (128 thr x 4 = 512 chunks)
    int srow[4], scol[4];
#pragma unroll
    for (int it = 0; it < 4; ++it) {
        int i = tid + it * 128;
        srow[it] = i >> 3;
        scol[it] = (i & 7) * 8;
    }

    // prefetch registers
    short8 sK[4], sV[4];
    float  biasn[4];

    // ---- prologue: prefetch first active block ----
    int kb = __builtin_ctz(mbits);
    mbits &= mbits - 1;
    {
        const short* kh = Khf_g + base + (size_t)kb * 64 * D_;
        const short* vt = Vtb_g + ((size_t)(bh * NB_ + kb)) * 64 * 64;
#pragma unroll
        for (int it = 0; it < 4; ++it) {
            sK[it] = *(const short8*)(kh + srow[it] * 64 + scol[it]);
            sV[it] = *(const short8*)(vt + srow[it] * 64 + scol[it]);
        }
#pragma unroll
        for (int t = 0; t < 4; ++t)
            biasn[t] = -1.0e6f * (1.0f - Msk[(size_t)b * S_ + kb * 64 + t * 16 + c]);
    }

    for (;;) {
        __syncthreads();   // all waves done reading LDS from previous iteration
        // ---- commit prefetched block to LDS ----
#pragma unroll
        for (int it = 0; it < 4; ++it) {
            *(short8*)&Kh[srow[it] * KP + scol[it]] = sK[it];
            *(short8*)&Vt[srow[it] * KP + scol[it]] = sV[it];
        }
        float biasc[4];
#pragma unroll
        for (int t = 0; t < 4; ++t) biasc[t] = biasn[t];
        __syncthreads();

        // ---- issue prefetch for the NEXT active block (overlaps compute) ----
        const bool have_next = (mbits != 0);
        if (have_next) {
            kb = __builtin_ctz(mbits);
            mbits &= mbits - 1;
            const short* kh = Khf_g + base + (size_t)kb * 64 * D_;
            const short* vt = Vtb_g + ((size_t)(bh * NB_ + kb)) * 64 * 64;
#pragma unroll
            for (int it = 0; it < 4; ++it) {
                sK[it] = *(const short8*)(kh + srow[it] * 64 + scol[it]);
                sV[it] = *(const short8*)(vt + srow[it] * 64 + scol[it]);
            }
#pragma unroll
            for (int t = 0; t < 4; ++t)
                biasn[t] = -1.0e6f * (1.0f - Msk[(size_t)b * S_ + kb * 64 + t * 16 + c]);
        }

        // ---- scores: single fp16 pass, 2 k-steps, 4 n-tiles = 8 MFMA ----
        float4_ sc[4];
#pragma unroll
        for (int t = 0; t < 4; ++t) { sc[t][0] = 0.f; sc[t][1] = 0.f; sc[t][2] = 0.f; sc[t][3] = 0.f; }
#pragma unroll
        for (int t = 0; t < 4; ++t) {
            const short* kp_ = &Kh[(t * 16 + c) * KP + quad * 8];
            half8_ kb0 = __builtin_bit_cast(half8_, *(const short8*)(kp_));
            half8_ kb1 = __builtin_bit_cast(half8_, *(const short8*)(kp_ + 32));
            sc[t] = __builtin_amdgcn_mfma_f32_16x16x32_f16(qa0, kb0, sc[t], 0, 0, 0);
            sc[t] = __builtin_amdgcn_mfma_f32_16x16x32_f16(qa1, kb1, sc[t], 0, 0, 0);
        }

        // ---- P = exp(s + bias); per-lane l partial; P -> per-wave LDS (bf16) ----
        short* Pw = Pl + wave * 16 * KP;
#pragma unroll
        for (int t = 0; t < 4; ++t) {
#pragma unroll
            for (int j = 0; j < 4; ++j) {
                float p = __expf(sc[t][j] + biasc[t]);
                l_part[j] += p;
                Pw[(quad * 4 + j) * KP + t * 16 + c] = f2bf(p);
            }
        }

        // ---- P A-frags (same-wave DS ordering) ----
        const short* pp = Pl + wave * 16 * KP + c * KP + quad * 8;
        short8 pa0 = *(const short8*)(pp);
        short8 pa1 = *(const short8*)(pp + 32);

        // ---- O += P * V (bf16) ----
#pragma unroll
        for (int t = 0; t < 4; ++t) {
            const short* vp = &Vt[(t * 16 + c) * KP + quad * 8];
            short8 vb0 = *(const short8*)(vp);
            short8 vb1 = *(const short8*)(vp + 32);
            o[t] = __builtin_amdgcn_mfma_f32_16x16x32_bf16(pa0, vb0, o[t], 0, 0, 0);
            o[t] = __builtin_amdgcn_mfma_f32_16x16x32_bf16(pa1, vb1, o[t], 0, 0, 0);
        }

        if (!have_next) break;
    }

    // ---- epilogue: reduce l across the 16 column-lanes once, normalize, store ----
#pragma unroll
    for (int j = 0; j < 4; ++j) {
        float rs = l_part[j];
        rs += __shfl_xor(rs, 1);
        rs += __shfl_xor(rs, 2);
        rs += __shfl_xor(rs, 4);
        rs += __shfl_xor(rs, 8);
        float inv = 1.0f / rs;
        size_t rowoff = base + (size_t)(qt * 32 + wave * 16 + quad * 4 + j) * D_;
#pragma unroll
        for (int t = 0; t < 4; ++t)
            O[rowoff + t * 16 + c] = o[t][j] * inv;
    }
}

// ---------------- fallback (no workspace): bf16 hi/lo LDS-staging kernel ----------------
__global__ __launch_bounds__(256, 2)
void attn_mfma_fb(const float* __restrict__ Q,
                  const float* __restrict__ K,
                  const float* __restrict__ V,
                  const float* __restrict__ Msk,
                  const int* __restrict__ Mat,
                  float* __restrict__ O) {
    __shared__ __align__(16) short lds[4 * 64 * KP];
    short* Khi = lds;
    short* Klo = lds + 64 * KP;
    short* Vt  = lds + 2 * 64 * KP;
    short* Pl  = lds + 3 * 64 * KP;

    const int tid  = threadIdx.x;
    const int wave = tid >> 6;
    const int lane = tid & 63;
    const int c    = lane & 15;
    const int quad = lane >> 4;

    const int qb = blockIdx.x;
    const int bh = blockIdx.y;
    const int b  = bh / H_;
    const size_t base = (size_t)bh * S_ * D_;

    short8 qh0, qh1, ql0, ql1;
    {
        const float* qp = Q + base + (size_t)(qb * 64 + wave * 16 + c) * D_ + quad * 8;
#pragma unroll
        for (int e = 0; e < 8; ++e) {
            float f0 = qp[e], f1 = qp[e + 32];
            qh0[e] = f2bf(f0); ql0[e] = f2bf(f0 - bf2f(qh0[e]));
            qh1[e] = f2bf(f1); ql1[e] = f2bf(f1 - bf2f(qh1[e]));
        }
    }

    float4_ o[4];
    float l_part[4];
#pragma unroll
    for (int t = 0; t < 4; ++t) { o[t][0] = 0.f; o[t][1] = 0.f; o[t][2] = 0.f; o[t][3] = 0.f; }
#pragma unroll
    for (int j = 0; j < 4; ++j) l_part[j] = 0.f;

    for (int kb = 0; kb < NB_; ++kb) {
        if (Mat[qb * NB_ + kb] == 0) continue;

        __syncthreads();
        {
            const float* kg = K + base + (size_t)kb * 64 * D_;
            const float* vg = V + base + (size_t)kb * 64 * D_;
#pragma unroll
            for (int it = 0; it < 4; ++it) {
                int i = tid + it * 256;
                int row = i >> 4, c4 = (i & 15) * 4;
                float4_ kv = *(const float4_*)(kg + row * D_ + c4);
                short4_ hi, lo;
#pragma unroll
                for (int e = 0; e < 4; ++e) {
                    hi[e] = f2bf(kv[e]);
                    lo[e] = f2bf(kv[e] - bf2f(hi[e]));
                }
                *(short4_*)&Khi[row * KP + c4] = hi;
                *(short4_*)&Klo[row * KP + c4] = lo;
                float4_ vv = *(const float4_*)(vg + row * D_ + c4);
#pragma unroll
                for (int e = 0; e < 4; ++e) Vt[(c4 + e) * KP + row] = f2bf(vv[e]);
            }
        }
        __syncthreads();

        float4_ sc[4];
#pragma unroll
        for (int t = 0; t < 4; ++t) { sc[t][0] = 0.f; sc[t][1] = 0.f; sc[t][2] = 0.f; sc[t][3] = 0.f; }
#pragma unroll
        for (int t = 0; t < 4; ++t) {
            const short* kph = &Khi[(t * 16 + c) * KP + quad * 8];
            const short* kpl = &Klo[(t * 16 + c) * KP + quad * 8];
            short8 kh0 = *(const short8*)(kph);
            short8 kh1 = *(const short8*)(kph + 32);
            short8 kl0 = *(const short8*)(kpl);
            short8 kl1 = *(const short8*)(kpl + 32);
            sc[t] = __builtin_amdgcn_mfma_f32_16x16x32_bf16(qh0, kh0, sc[t], 0, 0, 0);
            sc[t] = __builtin_amdgcn_mfma_f32_16x16x32_bf16(qh1, kh1, sc[t], 0, 0, 0);
            sc[t] = __builtin_amdgcn_mfma_f32_16x16x32_bf16(qh0, kl0, sc[t], 0, 0, 0);
            sc[t] = __builtin_amdgcn_mfma_f32_16x16x32_bf16(qh1, kl1, sc[t], 0, 0, 0);
            sc[t] = __builtin_amdgcn_mfma_f32_16x16x32_bf16(ql0, kh0, sc[t], 0, 0, 0);
            sc[t] = __builtin_amdgcn_mfma_f32_16x16x32_bf16(ql1, kh1, sc[t], 0, 0, 0);
        }

        short* Pw = Pl + wave * 16 * KP;
#pragma unroll
        for (int t = 0; t < 4; ++t) {
            float bias = -1.0e6f * (1.0f - Msk[(size_t)b * S_ + kb * 64 + t * 16 + c]);
#pragma unroll
            for (int j = 0; j < 4; ++j) {
                float p = __expf(sc[t][j] + bias);
                l_part[j] += p;
                Pw[(quad * 4 + j) * KP + t * 16 + c] = f2bf(p);
            }
        }

        const short* pp = Pl + wave * 16 * KP + c * KP + quad * 8;
        short8 pa0 = *(const short8*)(pp);
        short8 pa1 = *(const short8*)(pp + 32);

#pragma unroll
        for (int t = 0; t < 4; ++t) {
            const short* vp = &Vt[(t * 16 + c) * KP + quad * 8];
            short8 vb0 = *(const short8*)(vp);
            short8 vb1 = *(const short8*)(vp + 32);
            o[t] = __builtin_amdgcn_mfma_f32_16x16x32_bf16(pa0, vb0, o[t], 0, 0, 0);
            o[t] = __builtin_amdgcn_mfma_f32_16x16x32_bf16(pa1, vb1, o[t], 0, 0, 0);
        }
    }

#pragma unroll
    for (int j = 0; j < 4; ++j) {
        float rs = l_part[j];
        rs += __shfl_xor(rs, 1);
        rs += __shfl_xor(rs, 2);
        rs += __shfl_xor(rs, 4);
        rs += __shfl_xor(rs, 8);
        float inv = 1.0f / rs;
        size_t rowoff = base + (size_t)(qb * 64 + wave * 16 + quad * 4 + j) * D_;
#pragma unroll
        for (int t = 0; t < 4; ++t)
            O[rowoff + t * 16 + c] = o[t][j] * inv;
    }
}

extern "C" void kernel_launch(void* const* d_in, const int* in_sizes, int n_in,
                              void* d_out, int out_size, void* d_ws, size_t ws_size,
                              hipStream_t stream) {
    const float* q   = (const float*)d_in[0];
    const float* k   = (const float*)d_in[1];
    const float* v   = (const float*)d_in[2];
    const float* msk = (const float*)d_in[3];
    const int*   mat = (const int*)d_in[4];
    float*       out = (float*)d_out;

    const size_t elems = (size_t)B_ * H_ * S_ * D_;      // 2.1M
    const size_t need  = 2 * elems * sizeof(short);      // 8.4 MB
    const int use_pre  = (ws_size >= need) ? 1 : 0;      // deterministic per-call

    short* khf = (short*)d_ws;
    short* vtb = khf + elems;

    if (use_pre) {
        dim3 pgrid(NB_, B_ * H_);
        preconvert_kernel<<<pgrid, dim3(256), 0, stream>>>(k, v, khf, vtb);
        dim3 grid(S_ / 32, B_ * H_);                     // 64 x 16 = 1024 WGs, 128 thr
        attn_mfma_h<<<grid, dim3(128), 0, stream>>>(q, msk, mat, out, khf, vtb);
    } else {
        dim3 grid(NB_, B_ * H_);
        attn_mfma_fb<<<grid, dim3(256), 0, stream>>>(q, k, v, msk, mat, out);
    }
}